// Round 2
// baseline (577.816 us; speedup 1.0000x reference)
//
#include <hip/hip_runtime.h>
#include <cstdint>
#include <cstddef>

// ---------------- common ----------------
typedef __attribute__((ext_vector_type(8))) short short8;   // 8 x bf16 (4 VGPR)
typedef __attribute__((ext_vector_type(4))) short short4_;  // 4 x bf16
typedef __attribute__((ext_vector_type(4))) float f32x4;    // MFMA C/D

__device__ inline unsigned short bf16rne(float f) {
    uint32_t u = __builtin_bit_cast(uint32_t, f);
    u += 0x7fffu + ((u >> 16) & 1u);
    return (unsigned short)(u >> 16);
}

// async global->LDS, 16 B per lane. LDS dest = wave-uniform base + lane*16.
#define GLDS(g, l)                                                              \
    __builtin_amdgcn_global_load_lds(                                           \
        (const __attribute__((address_space(1))) void*)(g),                     \
        (__attribute__((address_space(3))) void*)(l), 16, 0, 0)

// ---------------- fp32 -> bf16 convert ----------------
__global__ void cvt_kernel(const float* __restrict__ src,
                           unsigned short* __restrict__ dst, int n8) {
    int i = blockIdx.x * blockDim.x + threadIdx.x;
    if (i >= n8) return;
    const float4* s = (const float4*)src + (size_t)i * 2;
    float4 a = s[0], b = s[1];
    uint32_t w0 = bf16rne(a.x) | ((uint32_t)bf16rne(a.y) << 16);
    uint32_t w1 = bf16rne(a.z) | ((uint32_t)bf16rne(a.w) << 16);
    uint32_t w2 = bf16rne(b.x) | ((uint32_t)bf16rne(b.y) << 16);
    uint32_t w3 = bf16rne(b.z) | ((uint32_t)bf16rne(b.w) << 16);
    uint4 o; o.x = w0; o.y = w1; o.z = w2; o.w = w3;
    ((uint4*)dst)[i] = o;
}

// ---------------- QKV projection GEMM (one batch-chunk: M=4096) ----------------
// C[i][n] = sum_k X[i][k] * W[n][k] + b[n];  M=4096 K=768 N=2304
// n -> (which,h,d): which=n/768, h=(n%768)/64, d=n%64
// q,k,v stored bf16 as (b_local*12+h, 1024, 64) row-major, b_local in [0,4).
__global__ __launch_bounds__(256) void qkv_gemm(
    const unsigned short* __restrict__ X, const unsigned short* __restrict__ W,
    const float* __restrict__ bqkv,
    unsigned short* __restrict__ qo, unsigned short* __restrict__ ko,
    unsigned short* __restrict__ vo)
{
    __shared__ unsigned short smem[16896];   // As[8192] Bs[8192] | epilogue Cs 128x132
    unsigned short* As = smem;
    unsigned short* Bs = smem + 8192;

    const int tid  = threadIdx.x;
    const int m0   = blockIdx.y * 128;
    const int n0   = blockIdx.x * 128;
    const int wid  = tid >> 6;
    const int lane = tid & 63;
    const int m16  = lane & 15;
    const int quad = lane >> 4;
    const int wm   = wid >> 1, wn = wid & 1;

    f32x4 acc[4][4];
    #pragma unroll
    for (int i = 0; i < 4; i++)
        #pragma unroll
        for (int j = 0; j < 4; j++) acc[i][j] = (f32x4){0.f, 0.f, 0.f, 0.f};

    for (int kt = 0; kt < 12; ++kt) {
        const int k0 = kt * 64;
        #pragma unroll
        for (int rd = 0; rd < 4; ++rd) {
            int id = rd * 256 + tid;
            int row = id >> 3, c = id & 7;
            GLDS(X + (size_t)(m0 + row) * 768 + k0 + c * 8, &As[id * 8]);
        }
        #pragma unroll
        for (int rd = 0; rd < 4; ++rd) {
            int id = rd * 256 + tid;
            int row = id >> 3, c = id & 7;
            GLDS(W + (size_t)(n0 + row) * 768 + k0 + c * 8, &Bs[id * 8]);
        }
        __syncthreads();
        #pragma unroll
        for (int ks = 0; ks < 2; ++ks) {
            short8 a[4], b[4];
            #pragma unroll
            for (int mb = 0; mb < 4; mb++)
                a[mb] = *(const short8*)&As[(wm * 64 + mb * 16 + m16) * 64 + ks * 32 + quad * 8];
            #pragma unroll
            for (int nb = 0; nb < 4; nb++)
                b[nb] = *(const short8*)&Bs[(wn * 64 + nb * 16 + m16) * 64 + ks * 32 + quad * 8];
            #pragma unroll
            for (int mb = 0; mb < 4; mb++)
                #pragma unroll
                for (int nb = 0; nb < 4; nb++)
                    acc[mb][nb] = __builtin_amdgcn_mfma_f32_16x16x32_bf16(
                        a[mb], b[nb], acc[mb][nb], 0, 0, 0);
        }
        __syncthreads();
    }

    // epilogue: bias, bf16, repack via LDS (stride 132: conflict-free scatter)
    float bias_n[4];
    #pragma unroll
    for (int nb = 0; nb < 4; nb++) bias_n[nb] = bqkv[n0 + wn * 64 + nb * 16 + m16];

    #pragma unroll
    for (int mb = 0; mb < 4; mb++)
        #pragma unroll
        for (int nb = 0; nb < 4; nb++)
            #pragma unroll
            for (int r = 0; r < 4; r++) {
                float v = acc[mb][nb][r] + bias_n[nb];
                smem[(wm * 64 + mb * 16 + quad * 4 + r) * 132 + wn * 64 + nb * 16 + m16] =
                    bf16rne(v);
            }
    __syncthreads();

    const int which = n0 / 768;
    const int hbase = (n0 % 768) / 64;
    unsigned short* outp = (which == 0) ? qo : (which == 1) ? ko : vo;
    const int bI  = m0 >> 10;      // local batch in [0,4)
    const int ns0 = m0 & 1023;
    #pragma unroll
    for (int rd = 0; rd < 8; ++rd) {
        int id = rd * 256 + tid;
        int row = id >> 4, c = id & 15;
        short4_ lo = *(const short4_*)&smem[row * 132 + c * 8];
        short4_ hi = *(const short4_*)&smem[row * 132 + c * 8 + 4];
        short8 v8 = __builtin_shufflevector(lo, hi, 0, 1, 2, 3, 4, 5, 6, 7);
        int h  = hbase + (c >> 3);
        int dc = (c & 7) * 8;
        unsigned short* dst =
            outp + ((size_t)(bI * 12 + h) * 1024 + ns0 + row) * 64 + dc;
        *(short8*)dst = v8;
    }
}

// ---------------- flash attention (one batch-chunk: 48 bh) ----------------
// grid (16 q-tiles, 48 bh). 4 waves; wave w owns q rows q0+w*16 .. +16.
__global__ __launch_bounds__(256) void attn_kernel(
    const unsigned short* __restrict__ Q, const unsigned short* __restrict__ K,
    const unsigned short* __restrict__ V, const float* __restrict__ bias,
    const float* __restrict__ dvec, float* __restrict__ out)
{
    __shared__ unsigned short smem[37120];
    unsigned short* Qs = smem;              // 64x64
    unsigned short* Ks = smem + 4096;       // 128x64
    unsigned short* Vs = smem + 12288;      // 128x64 (row-major V)
    unsigned short* Vt = smem + 20480;      // 64x128 (V^T)
    const int tid  = threadIdx.x;
    const int wid  = tid >> 6;
    const int lane = tid & 63;
    const int m16  = lane & 15;
    const int quad = lane >> 4;
    unsigned short* Ps = smem + 28672 + wid * 2112;  // per-wave 16x132

    const int bh = blockIdx.y;
    const int b = bh / 12, h = bh % 12;     // b = local batch in [0,4)
    const int q0 = blockIdx.x * 64;
    const unsigned short* Qb = Q + (size_t)bh * 65536;
    const unsigned short* Kb = K + (size_t)bh * 65536;
    const unsigned short* Vb = V + (size_t)bh * 65536;

    #pragma unroll
    for (int rd = 0; rd < 2; ++rd) {
        int id = rd * 256 + tid;
        int row = id >> 3, c = id & 7;
        GLDS(Qb + (size_t)(q0 + row) * 64 + c * 8, &Qs[id * 8]);
    }

    f32x4 acc_o[4];
    #pragma unroll
    for (int nb = 0; nb < 4; nb++) acc_o[nb] = (f32x4){0.f, 0.f, 0.f, 0.f};
    float m_i[4], l_i[4];
    #pragma unroll
    for (int r = 0; r < 4; r++) { m_i[r] = -3.0e38f; l_i[r] = 0.f; }

    const int qrow_base = q0 + wid * 16 + quad * 4;  // + r

    for (int kv = 0; kv < 8; ++kv) {
        const int k0 = kv * 128;
        #pragma unroll
        for (int rd = 0; rd < 4; ++rd) {
            int id = rd * 256 + tid;
            int row = id >> 3, c = id & 7;
            GLDS(Kb + (size_t)(k0 + row) * 64 + c * 8, &Ks[id * 8]);
        }
        #pragma unroll
        for (int rd = 0; rd < 4; ++rd) {
            int id = rd * 256 + tid;
            int row = id >> 3, c = id & 7;
            GLDS(Vb + (size_t)(k0 + row) * 64 + c * 8, &Vs[id * 8]);
        }
        __syncthreads();

        // LDS transpose V -> Vt (lanes write consecutive j: conflict-free)
        #pragma unroll
        for (int rd = 0; rd < 4; ++rd) {
            int id = rd * 256 + tid;
            int j = id & 127, c8 = id >> 7;
            short8 vv = *(const short8*)&Vs[j * 64 + c8 * 8];
            #pragma unroll
            for (int c = 0; c < 8; ++c)
                Vt[(c8 * 8 + c) * 128 + j] = (unsigned short)vv[c];
        }

        // bias prefetch (L2/L3-resident)
        float bv[8][4];
        const float* bp = bias + (size_t)qrow_base * 1024 + k0 + m16;
        #pragma unroll
        for (int cb = 0; cb < 8; cb++)
            #pragma unroll
            for (int r = 0; r < 4; r++)
                bv[cb][r] = bp[(size_t)r * 1024 + cb * 16];

        short8 aq0 = *(const short8*)&Qs[(wid * 16 + m16) * 64 + quad * 8];
        short8 aq1 = *(const short8*)&Qs[(wid * 16 + m16) * 64 + 32 + quad * 8];

        f32x4 s[8];
        #pragma unroll
        for (int cb = 0; cb < 8; cb++) {
            s[cb] = (f32x4){0.f, 0.f, 0.f, 0.f};
            short8 bk0 = *(const short8*)&Ks[(cb * 16 + m16) * 64 + quad * 8];
            short8 bk1 = *(const short8*)&Ks[(cb * 16 + m16) * 64 + 32 + quad * 8];
            s[cb] = __builtin_amdgcn_mfma_f32_16x16x32_bf16(aq0, bk0, s[cb], 0, 0, 0);
            s[cb] = __builtin_amdgcn_mfma_f32_16x16x32_bf16(aq1, bk1, s[cb], 0, 0, 0);
        }

        // scale + bias, online softmax (rows live in one 16-lane quad group)
        float mnew[4];
        #pragma unroll
        for (int r = 0; r < 4; r++) mnew[r] = -3.0e38f;
        #pragma unroll
        for (int cb = 0; cb < 8; cb++)
            #pragma unroll
            for (int r = 0; r < 4; r++) {
                float t = s[cb][r] * 0.125f + bv[cb][r];
                s[cb][r] = t;
                mnew[r] = fmaxf(mnew[r], t);
            }
        #pragma unroll
        for (int r = 0; r < 4; r++) {
            float mm = mnew[r];
            mm = fmaxf(mm, __shfl_xor(mm, 8, 64));
            mm = fmaxf(mm, __shfl_xor(mm, 4, 64));
            mm = fmaxf(mm, __shfl_xor(mm, 2, 64));
            mm = fmaxf(mm, __shfl_xor(mm, 1, 64));
            mnew[r] = mm;
        }
        float alpha[4], psum[4];
        #pragma unroll
        for (int r = 0; r < 4; r++) {
            float mt = fmaxf(m_i[r], mnew[r]);
            alpha[r] = __expf(m_i[r] - mt);
            m_i[r] = mt;
            psum[r] = 0.f;
        }
        #pragma unroll
        for (int cb = 0; cb < 8; cb++)
            #pragma unroll
            for (int r = 0; r < 4; r++) {
                float p = __expf(s[cb][r] - m_i[r]);
                psum[r] += p;
                Ps[(quad * 4 + r) * 132 + cb * 16 + m16] = bf16rne(p);
            }
        #pragma unroll
        for (int r = 0; r < 4; r++) {
            float ps = psum[r];
            ps += __shfl_xor(ps, 8, 64);
            ps += __shfl_xor(ps, 4, 64);
            ps += __shfl_xor(ps, 2, 64);
            ps += __shfl_xor(ps, 1, 64);
            l_i[r] = l_i[r] * alpha[r] + ps;
        }
        #pragma unroll
        for (int nb = 0; nb < 4; nb++)
            #pragma unroll
            for (int r = 0; r < 4; r++) acc_o[nb][r] *= alpha[r];

        __syncthreads();  // Vt ready for all waves

        // O += P * V   (P: A-frag from own-wave LDS; V^T: B-frag)
        #pragma unroll
        for (int ks = 0; ks < 4; ++ks) {
            short4_ plo = *(const short4_*)&Ps[m16 * 132 + ks * 32 + quad * 8];
            short4_ phi = *(const short4_*)&Ps[m16 * 132 + ks * 32 + quad * 8 + 4];
            short8 ap = __builtin_shufflevector(plo, phi, 0, 1, 2, 3, 4, 5, 6, 7);
            #pragma unroll
            for (int nb = 0; nb < 4; ++nb) {
                short8 bvv = *(const short8*)&Vt[(nb * 16 + m16) * 128 + ks * 32 + quad * 8];
                acc_o[nb] = __builtin_amdgcn_mfma_f32_16x16x32_bf16(ap, bvv, acc_o[nb], 0, 0, 0);
            }
        }
        __syncthreads();  // protect Ks/Vs/Vt before next tile's staging
    }

    // epilogue: out = d[row]/l * O ; out layout (4, 1024, 768) local chunk
    #pragma unroll
    for (int r = 0; r < 4; r++) {
        int row = qrow_base + r;
        float sc = dvec[row] / l_i[r];
        #pragma unroll
        for (int nb = 0; nb < 4; nb++)
            out[((size_t)b * 1024 + row) * 768 + h * 64 + nb * 16 + m16] =
                acc_o[nb][r] * sc;
    }
}

// ---------------- launch ----------------
// Workspace budget (ws usage = 22.4 MB; previous 104 MB overran ws_size and
// corrupted adjacent allocations -> post-timing divergence):
//   ws:   wb (3.54 MB) | q/k/v chunk (3 x 6.29 MB)
//   d_out upper half (bytes [25165824, 50331648)): xb (all 16 batches, bf16,
//   exactly 25165824 B). Stream order guarantees gemm_c consumes xb chunk c
//   before attn_{c'>=c} overwrites that region with final output.
extern "C" void kernel_launch(void* const* d_in, const int* in_sizes, int n_in,
                              void* d_out, int out_size, void* d_ws, size_t ws_size,
                              hipStream_t stream) {
    const float* x     = (const float*)d_in[0];   // (16,1024,768)
    const float* w     = (const float*)d_in[1];   // (2304,768)
    const float* bqkv  = (const float*)d_in[2];   // (2304,)
    const float* dvec  = (const float*)d_in[3];   // (1024,)
    const float* bbias = (const float*)d_in[4];   // (1024,1024)
    float* out = (float*)d_out;

    char* ws = (char*)d_ws;
    unsigned short* wb = (unsigned short*)ws;                        // 2304*768 bf16
    unsigned short* qb = (unsigned short*)(ws + 3538944);            // 4*12*1024*64 bf16
    unsigned short* kb = qb + 3145728;
    unsigned short* vb = kb + 3145728;
    unsigned short* xb = (unsigned short*)((char*)d_out + 25165824); // 16*1024*768 bf16

    cvt_kernel<<<6144, 256, 0, stream>>>(x, xb, 1572864);            // all x -> bf16
    cvt_kernel<<<864, 256, 0, stream>>>(w, wb, 221184);              // w -> bf16

    for (int c = 0; c < 4; ++c) {
        const unsigned short* xc = xb + (size_t)c * 3145728;         // 4 batches
        qkv_gemm<<<dim3(18, 32), 256, 0, stream>>>(xc, wb, bqkv, qb, kb, vb);
        attn_kernel<<<dim3(16, 48), 256, 0, stream>>>(
            qb, kb, vb, bbias, dvec, out + (size_t)c * 3145728);
    }
}

// Round 4
// 446.287 us; speedup vs baseline: 1.2947x; 1.2947x over previous
//
#include <hip/hip_runtime.h>
#include <cstdint>
#include <cstddef>

// ---------------- common ----------------
typedef __attribute__((ext_vector_type(8))) short short8;   // 8 x bf16 (4 VGPR)
typedef __attribute__((ext_vector_type(4))) short short4_;  // 4 x bf16 (2 VGPR)
typedef __attribute__((ext_vector_type(4))) float f32x4;    // MFMA C/D

__device__ inline unsigned short bf16rne(float f) {
    uint32_t u = __builtin_bit_cast(uint32_t, f);
    u += 0x7fffu + ((u >> 16) & 1u);
    return (unsigned short)(u >> 16);
}

// async global->LDS, 16 B per lane. LDS dest = wave-uniform base + lane*16.
// CONTRACT (m104/m108): data lands at base + laneid*16 regardless of per-lane
// pointer; layout must be hole-free in lane order, ALL 64 lanes active.
#define GLDS(g, l)                                                              \
    __builtin_amdgcn_global_load_lds(                                           \
        (const __attribute__((address_space(1))) void*)(g),                     \
        (__attribute__((address_space(3))) void*)(l), 16, 0, 0)

// ---------------- fp32 -> bf16 convert ----------------
__global__ void cvt_kernel(const float* __restrict__ src,
                           unsigned short* __restrict__ dst, int n8) {
    int i = blockIdx.x * blockDim.x + threadIdx.x;
    if (i >= n8) return;
    const float4* s = (const float4*)src + (size_t)i * 2;
    float4 a = s[0], b = s[1];
    uint32_t w0 = bf16rne(a.x) | ((uint32_t)bf16rne(a.y) << 16);
    uint32_t w1 = bf16rne(a.z) | ((uint32_t)bf16rne(a.w) << 16);
    uint32_t w2 = bf16rne(b.x) | ((uint32_t)bf16rne(b.y) << 16);
    uint32_t w3 = bf16rne(b.z) | ((uint32_t)bf16rne(b.w) << 16);
    uint4 o; o.x = w0; o.y = w1; o.z = w2; o.w = w3;
    ((uint4*)dst)[i] = o;
}

// ---------------- QKV projection GEMM (one batch-chunk: M=4096) ----------------
// C[i][n] = sum_k X[i][k] * W[n][k] + b[n];  M=4096 K=768 N=2304
// q,k stored bf16 as (b_local*12+h, 1024, 64) row-major.
// v stored TRANSPOSED: (b_local*12+h, 64, 1024)  [d-major, for attn PV A-frags]
__global__ __launch_bounds__(256) void qkv_gemm(
    const unsigned short* __restrict__ X, const unsigned short* __restrict__ W,
    const float* __restrict__ bqkv,
    unsigned short* __restrict__ qo, unsigned short* __restrict__ ko,
    unsigned short* __restrict__ vo)
{
    __shared__ unsigned short smem[16896];   // As[8192] Bs[8192] | epilogue Cs 128x132
    unsigned short* As = smem;
    unsigned short* Bs = smem + 8192;

    const int tid  = threadIdx.x;
    const int m0   = blockIdx.y * 128;
    const int n0   = blockIdx.x * 128;
    const int wid  = tid >> 6;
    const int lane = tid & 63;
    const int m16  = lane & 15;
    const int quad = lane >> 4;
    const int wm   = wid >> 1, wn = wid & 1;

    f32x4 acc[4][4];
    #pragma unroll
    for (int i = 0; i < 4; i++)
        #pragma unroll
        for (int j = 0; j < 4; j++) acc[i][j] = (f32x4){0.f, 0.f, 0.f, 0.f};

    for (int kt = 0; kt < 12; ++kt) {
        const int k0 = kt * 64;
        #pragma unroll
        for (int rd = 0; rd < 4; ++rd) {
            int id = rd * 256 + tid;
            int row = id >> 3, c = id & 7;
            GLDS(X + (size_t)(m0 + row) * 768 + k0 + c * 8, &As[id * 8]);
        }
        #pragma unroll
        for (int rd = 0; rd < 4; ++rd) {
            int id = rd * 256 + tid;
            int row = id >> 3, c = id & 7;
            GLDS(W + (size_t)(n0 + row) * 768 + k0 + c * 8, &Bs[id * 8]);
        }
        __syncthreads();
        #pragma unroll
        for (int ks = 0; ks < 2; ++ks) {
            short8 a[4], b[4];
            #pragma unroll
            for (int mb = 0; mb < 4; mb++)
                a[mb] = *(const short8*)&As[(wm * 64 + mb * 16 + m16) * 64 + ks * 32 + quad * 8];
            #pragma unroll
            for (int nb = 0; nb < 4; nb++)
                b[nb] = *(const short8*)&Bs[(wn * 64 + nb * 16 + m16) * 64 + ks * 32 + quad * 8];
            #pragma unroll
            for (int mb = 0; mb < 4; mb++)
                #pragma unroll
                for (int nb = 0; nb < 4; nb++)
                    acc[mb][nb] = __builtin_amdgcn_mfma_f32_16x16x32_bf16(
                        a[mb], b[nb], acc[mb][nb], 0, 0, 0);
        }
        __syncthreads();
    }

    float bias_n[4];
    #pragma unroll
    for (int nb = 0; nb < 4; nb++) bias_n[nb] = bqkv[n0 + wn * 64 + nb * 16 + m16];

    const int which = n0 / 768;
    const int hbase = (n0 % 768) / 64;
    const int bI  = m0 >> 10;      // local batch in [0,4)
    const int ns0 = m0 & 1023;

    if (which == 2) {
        // V: write transposed directly from acc (C-layout lane holds 4 consecutive
        // pos = quad*4+r for a fixed d-column) -> b64 stores into (bh,64,1024).
        #pragma unroll
        for (int mb = 0; mb < 4; ++mb)
            #pragma unroll
            for (int nb = 0; nb < 4; ++nb) {
                int n  = wn * 64 + nb * 16 + m16;
                int hh = hbase + (n >> 6);
                int d  = n & 63;
                int pos = ns0 + wm * 64 + mb * 16 + quad * 4;
                short4_ v4;
                #pragma unroll
                for (int r = 0; r < 4; ++r)
                    v4[r] = (short)bf16rne(acc[mb][nb][r] + bias_n[nb]);
                *(short4_*)(vo + ((size_t)(bI * 12 + hh) * 64 + d) * 1024 + pos) = v4;
            }
        return;
    }

    // Q/K: bias, bf16, repack via LDS (stride 132), row-major (bh,1024,64) stores
    #pragma unroll
    for (int mb = 0; mb < 4; mb++)
        #pragma unroll
        for (int nb = 0; nb < 4; nb++)
            #pragma unroll
            for (int r = 0; r < 4; r++) {
                float v = acc[mb][nb][r] + bias_n[nb];
                smem[(wm * 64 + mb * 16 + quad * 4 + r) * 132 + wn * 64 + nb * 16 + m16] =
                    bf16rne(v);
            }
    __syncthreads();

    unsigned short* outp = (which == 0) ? qo : ko;
    #pragma unroll
    for (int rd = 0; rd < 8; ++rd) {
        int id = rd * 256 + tid;
        int row = id >> 4, c = id & 15;
        short4_ lo = *(const short4_*)&smem[row * 132 + c * 8];
        short4_ hi = *(const short4_*)&smem[row * 132 + c * 8 + 4];
        short8 v8 = __builtin_shufflevector(lo, hi, 0, 1, 2, 3, 4, 5, 6, 7);
        int h  = hbase + (c >> 3);
        int dc = (c & 7) * 8;
        unsigned short* dst =
            outp + ((size_t)(bI * 12 + h) * 1024 + ns0 + row) * 64 + dc;
        *(short8*)dst = v8;
    }
}

// ---------------- flash attention (S^T formulation, one batch-chunk: 48 bh) ----
// grid (16 q-tiles, 48 bh). 4 waves; wave w owns q rows q0+w*16..+16.
// S^T = K·Q^T via 16x16x32 (C col = q-row, rows = pos) -> softmax is per-lane
// scalar state + 2 shuffles; P^T stays in registers as the B-frag of
// 16x16x16bf16_1k for O^T += V^T·P^T (no P LDS round-trip).
// LDS layouts are HOLE-FREE in GLDS lane order (R3 bug: predicated holes shift
// the whole wave's image) and bank-uniform:
//   Ks: slot = pos*8 + (db ^ (pos&7))  -> b128 reads hit 8 dwords/bank (min)
//   Vs: slot = pb*64 + d               -> b64  reads hit 4 dwords/bank (min)
__global__ __launch_bounds__(256, 3) void attn_kernel(
    const unsigned short* __restrict__ Q, const unsigned short* __restrict__ K,
    const unsigned short* __restrict__ Vt, const float* __restrict__ bias,
    const float* __restrict__ dvec, float* __restrict__ out)
{
    __shared__ unsigned short Ks[8192];   // 1024 slots * 8 elems = 16 KB
    __shared__ unsigned short Vs[8192];   // 1024 slots * 8 elems = 16 KB

    const int tid  = threadIdx.x;
    const int wid  = tid >> 6;
    const int lane = tid & 63;
    const int m16  = lane & 15;
    const int quad = lane >> 4;

    const int bh = blockIdx.y;
    const int b = bh / 12, h = bh % 12;     // b = local batch in [0,4)
    const int q0 = blockIdx.x * 64;
    const int qrow = q0 + wid * 16 + m16;   // this lane's q row (column of S^T)

    const unsigned short* Qb = Q  + (size_t)bh * 65536;
    const unsigned short* Kb = K  + (size_t)bh * 65536;
    const unsigned short* Vb = Vt + (size_t)bh * 65536;

    // kv-invariant staging source offsets (hole-free, all lanes active)
    int k_src[4], v_src[4];
    #pragma unroll
    for (int rd = 0; rd < 4; ++rd) {
        int id = rd * 256 + tid;
        int pos = id >> 3, dbs = id & 7;
        int db = dbs ^ (pos & 7);                 // un-swizzle: slot id holds this db
        k_src[rd] = pos * 64 + db * 8;
        int pb = id >> 6, d = id & 63;
        v_src[rd] = d * 1024 + pb * 8;
    }

    // Q fragments: B-operand of 16x16x32 (lane n=m16 holds dims quad*8..+8)
    short8 qf0 = *(const short8*)(Qb + (size_t)qrow * 64 + quad * 8);
    short8 qf1 = *(const short8*)(Qb + (size_t)qrow * 64 + 32 + quad * 8);

    f32x4 acc[4];
    #pragma unroll
    for (int nb = 0; nb < 4; nb++) acc[nb] = (f32x4){0.f, 0.f, 0.f, 0.f};
    float m_i = -3.0e38f, l_i = 0.f;

    for (int kv = 0; kv < 8; ++kv) {
        const int k0 = kv * 128;
        #pragma unroll
        for (int rd = 0; rd < 4; ++rd)
            GLDS(Kb + (size_t)k0 * 64 + k_src[rd], &Ks[(rd * 256 + tid) * 8]);
        #pragma unroll
        for (int rd = 0; rd < 4; ++rd)
            GLDS(Vb + (size_t)k0 + v_src[rd], &Vs[(rd * 256 + tid) * 8]);
        __syncthreads();

        // S^T = K·Q^T : sc[cb] rows = pos cb*16+quad*4+r, col = qrow(m16)
        f32x4 sc[8];
        #pragma unroll
        for (int cb = 0; cb < 8; ++cb) sc[cb] = (f32x4){0.f, 0.f, 0.f, 0.f};
        #pragma unroll
        for (int ks = 0; ks < 2; ++ks) {
            #pragma unroll
            for (int cb = 0; cb < 8; ++cb) {
                int pos = cb * 16 + m16;
                int slot = pos * 8 + ((ks * 4 + quad) ^ (m16 & 7));
                short8 a = *(const short8*)&Ks[slot * 8];
                sc[cb] = __builtin_amdgcn_mfma_f32_16x16x32_bf16(
                    a, (ks == 0) ? qf0 : qf1, sc[cb], 0, 0, 0);
            }
        }

        // scale + bias (float4 per cb) + running max (per-lane scalar)
        float mx = -3.0e38f;
        #pragma unroll
        for (int cb = 0; cb < 8; ++cb) {
            float4 bv = *(const float4*)(bias + (size_t)qrow * 1024 + k0 + cb * 16 + quad * 4);
            sc[cb][0] = sc[cb][0] * 0.125f + bv.x;
            sc[cb][1] = sc[cb][1] * 0.125f + bv.y;
            sc[cb][2] = sc[cb][2] * 0.125f + bv.z;
            sc[cb][3] = sc[cb][3] * 0.125f + bv.w;
            mx = fmaxf(mx, fmaxf(fmaxf(sc[cb][0], sc[cb][1]), fmaxf(sc[cb][2], sc[cb][3])));
        }
        mx = fmaxf(mx, __shfl_xor(mx, 16, 64));
        mx = fmaxf(mx, __shfl_xor(mx, 32, 64));
        float mnew = fmaxf(m_i, mx);
        float al = __expf(m_i - mnew);
        m_i = mnew;

        // exp + row-sum + pack P^T (registers; B-frag of 16x16x16: k=quad*4+r)
        float rs = 0.f;
        short4_ pf[8];
        #pragma unroll
        for (int cb = 0; cb < 8; ++cb) {
            float p0 = __expf(sc[cb][0] - m_i);
            float p1 = __expf(sc[cb][1] - m_i);
            float p2 = __expf(sc[cb][2] - m_i);
            float p3 = __expf(sc[cb][3] - m_i);
            rs += (p0 + p1) + (p2 + p3);
            short4_ p4;
            p4[0] = (short)bf16rne(p0); p4[1] = (short)bf16rne(p1);
            p4[2] = (short)bf16rne(p2); p4[3] = (short)bf16rne(p3);
            pf[cb] = p4;
        }
        rs += __shfl_xor(rs, 16, 64);
        rs += __shfl_xor(rs, 32, 64);
        l_i = l_i * al + rs;
        #pragma unroll
        for (int nb = 0; nb < 4; nb++) {
            acc[nb][0] *= al; acc[nb][1] *= al;
            acc[nb][2] *= al; acc[nb][3] *= al;
        }

        // O^T += V^T · P^T  (A = V^T frag from LDS, B = P^T in registers)
        #pragma unroll
        for (int ks = 0; ks < 8; ++ks) {
            #pragma unroll
            for (int nb = 0; nb < 4; ++nb) {
                int slot = (ks * 2 + (quad >> 1)) * 64 + nb * 16 + m16;
                short4_ av = *(const short4_*)&Vs[slot * 8 + (quad & 1) * 4];
                acc[nb] = __builtin_amdgcn_mfma_f32_16x16x16bf16_1k(av, pf[ks], acc[nb], 0, 0, 0);
            }
        }
        __syncthreads();
    }

    // epilogue: out = d[qrow]/l * O ; O^T C-layout: lane holds d = nb*16+quad*4+r
    float scl = dvec[qrow] / l_i;
    #pragma unroll
    for (int nb = 0; nb < 4; ++nb) {
        float4 o;
        o.x = acc[nb][0] * scl; o.y = acc[nb][1] * scl;
        o.z = acc[nb][2] * scl; o.w = acc[nb][3] * scl;
        *(float4*)(out + ((size_t)b * 1024 + qrow) * 768 + h * 64 + nb * 16 + quad * 4) = o;
    }
}

// ---------------- launch ----------------
// Workspace: ws = wb (3.54 MB) | q/k/vT chunk (3 x 6.29 MB)  => 22.4 MB.
// d_out upper half holds bf16 x (exactly 25165824 B); gemm_c consumes xb chunk c
// before attn_{c'>=c} overwrites that region with final output (stream-ordered).
extern "C" void kernel_launch(void* const* d_in, const int* in_sizes, int n_in,
                              void* d_out, int out_size, void* d_ws, size_t ws_size,
                              hipStream_t stream) {
    const float* x     = (const float*)d_in[0];   // (16,1024,768)
    const float* w     = (const float*)d_in[1];   // (2304,768)
    const float* bqkv  = (const float*)d_in[2];   // (2304,)
    const float* dvec  = (const float*)d_in[3];   // (1024,)
    const float* bbias = (const float*)d_in[4];   // (1024,1024)
    float* out = (float*)d_out;

    char* ws = (char*)d_ws;
    unsigned short* wb = (unsigned short*)ws;                        // 2304*768 bf16
    unsigned short* qb = (unsigned short*)(ws + 3538944);            // 4*12*1024*64
    unsigned short* kb = qb + 3145728;
    unsigned short* vb = kb + 3145728;                               // V^T (bh,64,1024)
    unsigned short* xb = (unsigned short*)((char*)d_out + 25165824); // 16*1024*768 bf16

    cvt_kernel<<<6144, 256, 0, stream>>>(x, xb, 1572864);            // all x -> bf16
    cvt_kernel<<<864, 256, 0, stream>>>(w, wb, 221184);              // w -> bf16

    for (int c = 0; c < 4; ++c) {
        const unsigned short* xc = xb + (size_t)c * 3145728;         // 4 batches
        qkv_gemm<<<dim3(18, 32), 256, 0, stream>>>(xc, wb, bqkv, qb, kb, vb);
        attn_kernel<<<dim3(16, 48), 256, 0, stream>>>(
            qb, kb, vb, bbias, dvec, out + (size_t)c * 3145728);
    }
}

// Round 5
// 393.548 us; speedup vs baseline: 1.4682x; 1.1340x over previous
//
#include <hip/hip_runtime.h>
#include <cstdint>
#include <cstddef>

// ---------------- common ----------------
typedef __attribute__((ext_vector_type(8))) short short8;   // 8 x bf16 (4 VGPR)
typedef __attribute__((ext_vector_type(4))) short short4_;  // 4 x bf16 (2 VGPR)
typedef __attribute__((ext_vector_type(4))) float f32x4;    // MFMA C/D

__device__ inline unsigned short bf16rne(float f) {
    uint32_t u = __builtin_bit_cast(uint32_t, f);
    u += 0x7fffu + ((u >> 16) & 1u);
    return (unsigned short)(u >> 16);
}

// async global->LDS, 16 B per lane. LDS dest = wave-uniform base + lane*16.
// CONTRACT (m104/m108): data lands at base + laneid*16 regardless of per-lane
// pointer; layout must be hole-free in lane order, ALL 64 lanes active.
#define GLDS(g, l)                                                              \
    __builtin_amdgcn_global_load_lds(                                           \
        (const __attribute__((address_space(1))) void*)(g),                     \
        (__attribute__((address_space(3))) void*)(l), 16, 0, 0)

// ---------------- fp32 -> bf16 convert ----------------
__global__ void cvt_kernel(const float* __restrict__ src,
                           unsigned short* __restrict__ dst, int n8) {
    int i = blockIdx.x * blockDim.x + threadIdx.x;
    if (i >= n8) return;
    const float4* s = (const float4*)src + (size_t)i * 2;
    float4 a = s[0], b = s[1];
    uint32_t w0 = bf16rne(a.x) | ((uint32_t)bf16rne(a.y) << 16);
    uint32_t w1 = bf16rne(a.z) | ((uint32_t)bf16rne(a.w) << 16);
    uint32_t w2 = bf16rne(b.x) | ((uint32_t)bf16rne(b.y) << 16);
    uint32_t w3 = bf16rne(b.z) | ((uint32_t)bf16rne(b.w) << 16);
    uint4 o; o.x = w0; o.y = w1; o.z = w2; o.w = w3;
    ((uint4*)dst)[i] = o;
}

// ---------------- QKV projection GEMM ----------------
// C[i][n] = sum_k X[i][k] * W[n][k] + b[n];  M = 128*gridDim.y, K=768, N=2304
// q,k stored bf16 as (b_local*12+h, 1024, 64) row-major.
// v stored TRANSPOSED: (b_local*12+h, 64, 1024)  [d-major, for attn PV A-frags]
__global__ __launch_bounds__(256) void qkv_gemm(
    const unsigned short* __restrict__ X, const unsigned short* __restrict__ W,
    const float* __restrict__ bqkv,
    unsigned short* __restrict__ qo, unsigned short* __restrict__ ko,
    unsigned short* __restrict__ vo)
{
    __shared__ unsigned short smem[16896];   // As[8192] Bs[8192] | epilogue Cs 128x132
    unsigned short* As = smem;
    unsigned short* Bs = smem + 8192;

    const int tid  = threadIdx.x;
    const int m0   = blockIdx.y * 128;
    const int n0   = blockIdx.x * 128;
    const int wid  = tid >> 6;
    const int lane = tid & 63;
    const int m16  = lane & 15;
    const int quad = lane >> 4;
    const int wm   = wid >> 1, wn = wid & 1;

    f32x4 acc[4][4];
    #pragma unroll
    for (int i = 0; i < 4; i++)
        #pragma unroll
        for (int j = 0; j < 4; j++) acc[i][j] = (f32x4){0.f, 0.f, 0.f, 0.f};

    for (int kt = 0; kt < 12; ++kt) {
        const int k0 = kt * 64;
        #pragma unroll
        for (int rd = 0; rd < 4; ++rd) {
            int id = rd * 256 + tid;
            int row = id >> 3, c = id & 7;
            GLDS(X + (size_t)(m0 + row) * 768 + k0 + c * 8, &As[id * 8]);
        }
        #pragma unroll
        for (int rd = 0; rd < 4; ++rd) {
            int id = rd * 256 + tid;
            int row = id >> 3, c = id & 7;
            GLDS(W + (size_t)(n0 + row) * 768 + k0 + c * 8, &Bs[id * 8]);
        }
        __syncthreads();
        #pragma unroll
        for (int ks = 0; ks < 2; ++ks) {
            short8 a[4], b[4];
            #pragma unroll
            for (int mb = 0; mb < 4; mb++)
                a[mb] = *(const short8*)&As[(wm * 64 + mb * 16 + m16) * 64 + ks * 32 + quad * 8];
            #pragma unroll
            for (int nb = 0; nb < 4; nb++)
                b[nb] = *(const short8*)&Bs[(wn * 64 + nb * 16 + m16) * 64 + ks * 32 + quad * 8];
            #pragma unroll
            for (int mb = 0; mb < 4; mb++)
                #pragma unroll
                for (int nb = 0; nb < 4; nb++)
                    acc[mb][nb] = __builtin_amdgcn_mfma_f32_16x16x32_bf16(
                        a[mb], b[nb], acc[mb][nb], 0, 0, 0);
        }
        __syncthreads();
    }

    float bias_n[4];
    #pragma unroll
    for (int nb = 0; nb < 4; nb++) bias_n[nb] = bqkv[n0 + wn * 64 + nb * 16 + m16];

    const int which = n0 / 768;
    const int hbase = (n0 % 768) / 64;
    const int bI  = m0 >> 10;      // batch index
    const int ns0 = m0 & 1023;

    if (which == 2) {
        // V: write transposed directly from acc (C-layout lane holds 4 consecutive
        // pos = quad*4+r for a fixed d-column) -> b64 stores into (bh,64,1024).
        #pragma unroll
        for (int mb = 0; mb < 4; ++mb)
            #pragma unroll
            for (int nb = 0; nb < 4; ++nb) {
                int n  = wn * 64 + nb * 16 + m16;
                int hh = hbase + (n >> 6);
                int d  = n & 63;
                int pos = ns0 + wm * 64 + mb * 16 + quad * 4;
                short4_ v4;
                #pragma unroll
                for (int r = 0; r < 4; ++r)
                    v4[r] = (short)bf16rne(acc[mb][nb][r] + bias_n[nb]);
                *(short4_*)(vo + ((size_t)(bI * 12 + hh) * 64 + d) * 1024 + pos) = v4;
            }
        return;
    }

    // Q/K: bias, bf16, repack via LDS (stride 132), row-major (bh,1024,64) stores
    #pragma unroll
    for (int mb = 0; mb < 4; mb++)
        #pragma unroll
        for (int nb = 0; nb < 4; nb++)
            #pragma unroll
            for (int r = 0; r < 4; r++) {
                float v = acc[mb][nb][r] + bias_n[nb];
                smem[(wm * 64 + mb * 16 + quad * 4 + r) * 132 + wn * 64 + nb * 16 + m16] =
                    bf16rne(v);
            }
    __syncthreads();

    unsigned short* outp = (which == 0) ? qo : ko;
    #pragma unroll
    for (int rd = 0; rd < 8; ++rd) {
        int id = rd * 256 + tid;
        int row = id >> 4, c = id & 15;
        short4_ lo = *(const short4_*)&smem[row * 132 + c * 8];
        short4_ hi = *(const short4_*)&smem[row * 132 + c * 8 + 4];
        short8 v8 = __builtin_shufflevector(lo, hi, 0, 1, 2, 3, 4, 5, 6, 7);
        int h  = hbase + (c >> 3);
        int dc = (c & 7) * 8;
        unsigned short* dst =
            outp + ((size_t)(bI * 12 + h) * 1024 + ns0 + row) * 64 + dc;
        *(short8*)dst = v8;
    }
}

// ---------------- flash attention (S^T formulation, double-buffered) ----------
// grid (16 q-tiles, nbh). 4 waves; wave w owns q rows q0+w*16..+16.
// S^T = K·Q^T via 16x16x32 (C col = q-row, rows = pos) -> softmax is per-lane
// scalar state + 2 shuffles; P^T stays in registers as the B-frag of
// 16x16x16bf16_1k for O^T += V^T·P^T (no P LDS round-trip).
// K/V staged with GLDS into DOUBLE-BUFFERED hole-free bank-uniform layouts:
//   Ks: slot = pos*8 + (db ^ (pos&7))  -> b128 reads hit 8 dwords/bank (min)
//   Vs: slot = pb*64 + d               -> b64  reads hit 4 dwords/bank (min)
// One barrier per kv-iter; tile k+1's GLDS issues right after the barrier so
// compute(k) covers the load latency (the overlap the 2-barrier shape lacked).
__global__ __launch_bounds__(256, 2) void attn_kernel(
    const unsigned short* __restrict__ Q, const unsigned short* __restrict__ K,
    const unsigned short* __restrict__ Vt, const float* __restrict__ bias,
    const float* __restrict__ dvec, float* __restrict__ out)
{
    __shared__ unsigned short Ks[2][8192];   // 2 x 16 KB
    __shared__ unsigned short Vs[2][8192];   // 2 x 16 KB

    const int tid  = threadIdx.x;
    const int wid  = tid >> 6;
    const int lane = tid & 63;
    const int m16  = lane & 15;
    const int quad = lane >> 4;

    const int bh = blockIdx.y;
    const int b = bh / 12, h = bh % 12;
    const int q0 = blockIdx.x * 64;
    const int qrow = q0 + wid * 16 + m16;   // this lane's q row (column of S^T)

    const unsigned short* Qb = Q  + (size_t)bh * 65536;
    const unsigned short* Kb = K  + (size_t)bh * 65536;
    const unsigned short* Vb = Vt + (size_t)bh * 65536;

    // kv-invariant staging source offsets (hole-free, all lanes active)
    int k_src[4], v_src[4];
    #pragma unroll
    for (int rd = 0; rd < 4; ++rd) {
        int id = rd * 256 + tid;
        int pos = id >> 3, dbs = id & 7;
        int db = dbs ^ (pos & 7);                 // un-swizzle: slot id holds this db
        k_src[rd] = pos * 64 + db * 8;
        int pb = id >> 6, d = id & 63;
        v_src[rd] = d * 1024 + pb * 8;
    }

    // Q fragments: B-operand of 16x16x32 (lane n=m16 holds dims quad*8..+8)
    short8 qf0 = *(const short8*)(Qb + (size_t)qrow * 64 + quad * 8);
    short8 qf1 = *(const short8*)(Qb + (size_t)qrow * 64 + 32 + quad * 8);

    f32x4 acc[4];
    #pragma unroll
    for (int nb = 0; nb < 4; nb++) acc[nb] = (f32x4){0.f, 0.f, 0.f, 0.f};
    float m_i = -3.0e38f, l_i = 0.f;

    // prologue: stage tile 0 into buffer 0
    #pragma unroll
    for (int rd = 0; rd < 4; ++rd)
        GLDS(Kb + k_src[rd], &Ks[0][(rd * 256 + tid) * 8]);
    #pragma unroll
    for (int rd = 0; rd < 4; ++rd)
        GLDS(Vb + v_src[rd], &Vs[0][(rd * 256 + tid) * 8]);

    for (int kv = 0; kv < 8; ++kv) {
        const int k0 = kv * 128;
        __syncthreads();   // vmcnt(0) drain: buf[kv&1] staged; buf[1-kv&1] free

        // prefetch tile kv+1 into the other buffer (wave-uniform condition)
        if (kv < 7) {
            const int kn = (kv + 1) * 128;
            unsigned short* Kn = Ks[(kv + 1) & 1];
            unsigned short* Vn = Vs[(kv + 1) & 1];
            #pragma unroll
            for (int rd = 0; rd < 4; ++rd)
                GLDS(Kb + (size_t)kn * 64 + k_src[rd], &Kn[(rd * 256 + tid) * 8]);
            #pragma unroll
            for (int rd = 0; rd < 4; ++rd)
                GLDS(Vb + (size_t)kn + v_src[rd], &Vn[(rd * 256 + tid) * 8]);
        }

        const unsigned short* Kc = Ks[kv & 1];
        const unsigned short* Vc = Vs[kv & 1];

        // S^T = K·Q^T : sc[cb] rows = pos cb*16+quad*4+r, col = qrow(m16)
        f32x4 sc[8];
        #pragma unroll
        for (int cb = 0; cb < 8; ++cb) sc[cb] = (f32x4){0.f, 0.f, 0.f, 0.f};
        #pragma unroll
        for (int ks = 0; ks < 2; ++ks) {
            #pragma unroll
            for (int cb = 0; cb < 8; ++cb) {
                int pos = cb * 16 + m16;
                int slot = pos * 8 + ((ks * 4 + quad) ^ (m16 & 7));
                short8 a = *(const short8*)&Kc[slot * 8];
                sc[cb] = __builtin_amdgcn_mfma_f32_16x16x32_bf16(
                    a, (ks == 0) ? qf0 : qf1, sc[cb], 0, 0, 0);
            }
        }

        // scale + bias (float4 per cb) + running max (per-lane scalar)
        float mx = -3.0e38f;
        #pragma unroll
        for (int cb = 0; cb < 8; ++cb) {
            float4 bv = *(const float4*)(bias + (size_t)qrow * 1024 + k0 + cb * 16 + quad * 4);
            sc[cb][0] = sc[cb][0] * 0.125f + bv.x;
            sc[cb][1] = sc[cb][1] * 0.125f + bv.y;
            sc[cb][2] = sc[cb][2] * 0.125f + bv.z;
            sc[cb][3] = sc[cb][3] * 0.125f + bv.w;
            mx = fmaxf(mx, fmaxf(fmaxf(sc[cb][0], sc[cb][1]), fmaxf(sc[cb][2], sc[cb][3])));
        }
        mx = fmaxf(mx, __shfl_xor(mx, 16, 64));
        mx = fmaxf(mx, __shfl_xor(mx, 32, 64));
        float mnew = fmaxf(m_i, mx);
        float al = __expf(m_i - mnew);
        m_i = mnew;

        // exp + row-sum + pack P^T (registers; B-frag of 16x16x16: k=quad*4+r)
        float rs = 0.f;
        short4_ pf[8];
        #pragma unroll
        for (int cb = 0; cb < 8; ++cb) {
            float p0 = __expf(sc[cb][0] - m_i);
            float p1 = __expf(sc[cb][1] - m_i);
            float p2 = __expf(sc[cb][2] - m_i);
            float p3 = __expf(sc[cb][3] - m_i);
            rs += (p0 + p1) + (p2 + p3);
            short4_ p4;
            p4[0] = (short)bf16rne(p0); p4[1] = (short)bf16rne(p1);
            p4[2] = (short)bf16rne(p2); p4[3] = (short)bf16rne(p3);
            pf[cb] = p4;
        }
        rs += __shfl_xor(rs, 16, 64);
        rs += __shfl_xor(rs, 32, 64);
        l_i = l_i * al + rs;
        #pragma unroll
        for (int nb = 0; nb < 4; nb++) {
            acc[nb][0] *= al; acc[nb][1] *= al;
            acc[nb][2] *= al; acc[nb][3] *= al;
        }

        // O^T += V^T · P^T  (A = V^T frag from LDS, B = P^T in registers)
        #pragma unroll
        for (int ks = 0; ks < 8; ++ks) {
            #pragma unroll
            for (int nb = 0; nb < 4; ++nb) {
                int slot = (ks * 2 + (quad >> 1)) * 64 + nb * 16 + m16;
                short4_ av = *(const short4_*)&Vc[slot * 8 + (quad & 1) * 4];
                acc[nb] = __builtin_amdgcn_mfma_f32_16x16x16bf16_1k(av, pf[ks], acc[nb], 0, 0, 0);
            }
        }
    }

    // epilogue: out = d[qrow]/l * O ; O^T C-layout: lane holds d = nb*16+quad*4+r
    float scl = dvec[qrow] / l_i;
    #pragma unroll
    for (int nb = 0; nb < 4; ++nb) {
        float4 o;
        o.x = acc[nb][0] * scl; o.y = acc[nb][1] * scl;
        o.z = acc[nb][2] * scl; o.w = acc[nb][3] * scl;
        *(float4*)(out + ((size_t)b * 1024 + qrow) * 768 + h * 64 + nb * 16 + quad * 4) = o;
    }
}

// ---------------- launch ----------------
// xb (bf16 x, 25165824 B) lives in the upper half of d_out; every gemm that
// reads an xb region precedes (stream order) any attn write to that region.
// Workspace is layout-adaptive on ws_size (constant across calls => the same
// work every call):
//   full path  (ws >= 79,036,416 B): wb + full-size q/k/vT  -> 1 gemm + 1 attn
//   chunk path (ws >= 22,413,312 B): wb + 4-batch q/k/vT    -> 4x(gemm+attn)
extern "C" void kernel_launch(void* const* d_in, const int* in_sizes, int n_in,
                              void* d_out, int out_size, void* d_ws, size_t ws_size,
                              hipStream_t stream) {
    const float* x     = (const float*)d_in[0];   // (16,1024,768)
    const float* w     = (const float*)d_in[1];   // (2304,768)
    const float* bqkv  = (const float*)d_in[2];   // (2304,)
    const float* dvec  = (const float*)d_in[3];   // (1024,)
    const float* bbias = (const float*)d_in[4];   // (1024,1024)
    float* out = (float*)d_out;

    char* ws = (char*)d_ws;
    unsigned short* wb = (unsigned short*)ws;                        // 2304*768 bf16
    unsigned short* xb = (unsigned short*)((char*)d_out + 25165824); // 16*1024*768 bf16

    cvt_kernel<<<6144, 256, 0, stream>>>(x, xb, 1572864);            // all x -> bf16
    cvt_kernel<<<864, 256, 0, stream>>>(w, wb, 221184);              // w -> bf16

    const size_t NEED_FULL = 3538944ull + 3ull * 25165824ull;        // 79,036,416
    if (ws_size >= NEED_FULL) {
        unsigned short* qb = (unsigned short*)(ws + 3538944);        // 16*12*1024*64
        unsigned short* kb = qb + 12582912;
        unsigned short* vb = kb + 12582912;                          // V^T (bh,64,1024)
        qkv_gemm<<<dim3(18, 128), 256, 0, stream>>>(xb, wb, bqkv, qb, kb, vb);
        attn_kernel<<<dim3(16, 192), 256, 0, stream>>>(qb, kb, vb, bbias, dvec, out);
    } else {
        unsigned short* qb = (unsigned short*)(ws + 3538944);        // 4*12*1024*64
        unsigned short* kb = qb + 3145728;
        unsigned short* vb = kb + 3145728;                           // V^T (bh,64,1024)
        for (int c = 0; c < 4; ++c) {
            const unsigned short* xc = xb + (size_t)c * 3145728;     // 4 batches
            qkv_gemm<<<dim3(18, 32), 256, 0, stream>>>(xc, wb, bqkv, qb, kb, vb);
            attn_kernel<<<dim3(16, 48), 256, 0, stream>>>(
                qb, kb, vb, bbias, dvec, out + (size_t)c * 3145728);
        }
    }
}

// Round 6
// 378.361 us; speedup vs baseline: 1.5272x; 1.0401x over previous
//
#include <hip/hip_runtime.h>
#include <cstdint>
#include <cstddef>

// ---------------- common ----------------
typedef __attribute__((ext_vector_type(8))) short short8;   // 8 x bf16 (4 VGPR)
typedef __attribute__((ext_vector_type(4))) short short4_;  // 4 x bf16 (2 VGPR)
typedef __attribute__((ext_vector_type(4))) float f32x4;    // MFMA C/D
typedef __attribute__((ext_vector_type(2))) unsigned int uint2_;

__device__ inline unsigned short bf16rne(float f) {
    uint32_t u = __builtin_bit_cast(uint32_t, f);
    u += 0x7fffu + ((u >> 16) & 1u);
    return (unsigned short)(u >> 16);
}

// async global->LDS, 16 B per lane. LDS dest = wave-uniform base + lane*16.
// CONTRACT (m104/m108): data lands at base + laneid*16 regardless of per-lane
// pointer; layout must be hole-free in lane order, ALL 64 lanes active.
#define GLDS(g, l)                                                              \
    __builtin_amdgcn_global_load_lds(                                           \
        (const __attribute__((address_space(1))) void*)(g),                     \
        (__attribute__((address_space(3))) void*)(l), 16, 0, 0)

// ---------------- fp32 -> bf16 convert ----------------
__global__ void cvt_kernel(const float* __restrict__ src,
                           unsigned short* __restrict__ dst, int n8) {
    int i = blockIdx.x * blockDim.x + threadIdx.x;
    if (i >= n8) return;
    const float4* s = (const float4*)src + (size_t)i * 2;
    float4 a = s[0], b = s[1];
    uint32_t w0 = bf16rne(a.x) | ((uint32_t)bf16rne(a.y) << 16);
    uint32_t w1 = bf16rne(a.z) | ((uint32_t)bf16rne(a.w) << 16);
    uint32_t w2 = bf16rne(b.x) | ((uint32_t)bf16rne(b.y) << 16);
    uint32_t w3 = bf16rne(b.z) | ((uint32_t)bf16rne(b.w) << 16);
    uint4 o; o.x = w0; o.y = w1; o.z = w2; o.w = w3;
    ((uint4*)dst)[i] = o;
}

// ---------------- QKV projection GEMM ----------------
// C[i][n] = sum_k X[i][k] * W[n][k] + b[n];  M = 128*gridDim.y, K=768, N=2304
// q,k stored bf16 as (b*12+h, 1024, 64) row-major.
// v stored TRANSPOSED: (b*12+h, 64, 1024)  [d-major, for attn PV A-frags]
__global__ __launch_bounds__(256) void qkv_gemm(
    const unsigned short* __restrict__ X, const unsigned short* __restrict__ W,
    const float* __restrict__ bqkv,
    unsigned short* __restrict__ qo, unsigned short* __restrict__ ko,
    unsigned short* __restrict__ vo)
{
    __shared__ unsigned short smem[16896];   // As[8192] Bs[8192] | epilogue Cs 128x132
    unsigned short* As = smem;
    unsigned short* Bs = smem + 8192;

    const int tid  = threadIdx.x;
    const int m0   = blockIdx.y * 128;
    const int n0   = blockIdx.x * 128;
    const int wid  = tid >> 6;
    const int lane = tid & 63;
    const int m16  = lane & 15;
    const int quad = lane >> 4;
    const int wm   = wid >> 1, wn = wid & 1;

    f32x4 acc[4][4];
    #pragma unroll
    for (int i = 0; i < 4; i++)
        #pragma unroll
        for (int j = 0; j < 4; j++) acc[i][j] = (f32x4){0.f, 0.f, 0.f, 0.f};

    for (int kt = 0; kt < 12; ++kt) {
        const int k0 = kt * 64;
        #pragma unroll
        for (int rd = 0; rd < 4; ++rd) {
            int id = rd * 256 + tid;
            int row = id >> 3, c = id & 7;
            GLDS(X + (size_t)(m0 + row) * 768 + k0 + c * 8, &As[id * 8]);
        }
        #pragma unroll
        for (int rd = 0; rd < 4; ++rd) {
            int id = rd * 256 + tid;
            int row = id >> 3, c = id & 7;
            GLDS(W + (size_t)(n0 + row) * 768 + k0 + c * 8, &Bs[id * 8]);
        }
        __syncthreads();
        #pragma unroll
        for (int ks = 0; ks < 2; ++ks) {
            short8 a[4], b[4];
            #pragma unroll
            for (int mb = 0; mb < 4; mb++)
                a[mb] = *(const short8*)&As[(wm * 64 + mb * 16 + m16) * 64 + ks * 32 + quad * 8];
            #pragma unroll
            for (int nb = 0; nb < 4; nb++)
                b[nb] = *(const short8*)&Bs[(wn * 64 + nb * 16 + m16) * 64 + ks * 32 + quad * 8];
            #pragma unroll
            for (int mb = 0; mb < 4; mb++)
                #pragma unroll
                for (int nb = 0; nb < 4; nb++)
                    acc[mb][nb] = __builtin_amdgcn_mfma_f32_16x16x32_bf16(
                        a[mb], b[nb], acc[mb][nb], 0, 0, 0);
        }
        __syncthreads();
    }

    float bias_n[4];
    #pragma unroll
    for (int nb = 0; nb < 4; nb++) bias_n[nb] = bqkv[n0 + wn * 64 + nb * 16 + m16];

    const int which = n0 / 768;
    const int hbase = (n0 % 768) / 64;
    const int bI  = m0 >> 10;      // batch index
    const int ns0 = m0 & 1023;

    if (which == 2) {
        // V: write transposed directly from acc (C-layout lane holds 4 consecutive
        // pos = quad*4+r for a fixed d-column) -> b64 stores into (bh,64,1024).
        #pragma unroll
        for (int mb = 0; mb < 4; ++mb)
            #pragma unroll
            for (int nb = 0; nb < 4; ++nb) {
                int n  = wn * 64 + nb * 16 + m16;
                int hh = hbase + (n >> 6);
                int d  = n & 63;
                int pos = ns0 + wm * 64 + mb * 16 + quad * 4;
                short4_ v4;
                #pragma unroll
                for (int r = 0; r < 4; ++r)
                    v4[r] = (short)bf16rne(acc[mb][nb][r] + bias_n[nb]);
                *(short4_*)(vo + ((size_t)(bI * 12 + hh) * 64 + d) * 1024 + pos) = v4;
            }
        return;
    }

    // Q/K: bias, bf16, repack via LDS (stride 132), row-major (bh,1024,64) stores
    #pragma unroll
    for (int mb = 0; mb < 4; mb++)
        #pragma unroll
        for (int nb = 0; nb < 4; nb++)
            #pragma unroll
            for (int r = 0; r < 4; r++) {
                float v = acc[mb][nb][r] + bias_n[nb];
                smem[(wm * 64 + mb * 16 + quad * 4 + r) * 132 + wn * 64 + nb * 16 + m16] =
                    bf16rne(v);
            }
    __syncthreads();

    unsigned short* outp = (which == 0) ? qo : ko;
    #pragma unroll
    for (int rd = 0; rd < 8; ++rd) {
        int id = rd * 256 + tid;
        int row = id >> 4, c = id & 15;
        short4_ lo = *(const short4_*)&smem[row * 132 + c * 8];
        short4_ hi = *(const short4_*)&smem[row * 132 + c * 8 + 4];
        short8 v8 = __builtin_shufflevector(lo, hi, 0, 1, 2, 3, 4, 5, 6, 7);
        int h  = hbase + (c >> 3);
        int dc = (c & 7) * 8;
        unsigned short* dst =
            outp + ((size_t)(bI * 12 + h) * 1024 + ns0 + row) * 64 + dc;
        *(short8*)dst = v8;
    }
}

// ---------------- flash attention (S^T formulation, single-buffer) ------------
// 1-D grid nbh*16, XCD-swizzled: f=(xcd | 8*(q | 16*bhl)), bh=xcd*nbh8+bhl.
// All 16 q-tiles of one bh land on one XCD (block f -> XCD f%8 heuristic) so
// K/V stay L2-resident per XCD (R5 FETCH 221 MB vs ~80 MB unique).
// 4 waves; wave w owns q rows q0+w*16..+16.
// S^T = K·Q^T via 16x16x32 (C col = q-row, rows = pos) -> softmax is per-lane
// scalar state + 2 shuffles; P^T packed in registers via v_perm_b32 truncation
// (B-frag of 16x16x16bf16_1k) for O^T += V^T·P^T (no P LDS round-trip).
// LDS 32 KB single-buffer -> 5 blocks/CU: inter-block wave overlap is the
// pipelining (R5 lesson: dbuf at 64 KB LDS traded occupancy 1:1, net zero).
//   Ks: slot = pos*8 + (db ^ (pos&7))  -> b128 reads hit 8 dwords/bank (min)
//   Vs: slot = pb*64 + d               -> b64  reads hit 4 dwords/bank (min)
__global__ __launch_bounds__(256, 5) void attn_kernel(
    const unsigned short* __restrict__ Q, const unsigned short* __restrict__ K,
    const unsigned short* __restrict__ Vt, const float* __restrict__ bias,
    const float* __restrict__ dvec, float* __restrict__ out, int nbh8)
{
    __shared__ unsigned short Ks[8192];   // 1024 slots * 8 elems = 16 KB
    __shared__ unsigned short Vs[8192];   // 1024 slots * 8 elems = 16 KB

    const int tid  = threadIdx.x;
    const int wid  = tid >> 6;
    const int lane = tid & 63;
    const int m16  = lane & 15;
    const int quad = lane >> 4;

    const int f    = blockIdx.x;
    const int xcd  = f & 7;
    const int r_   = f >> 3;
    const int qt   = r_ & 15;
    const int bhl  = r_ >> 4;
    const int bh   = xcd * nbh8 + bhl;
    const int b = bh / 12, h = bh % 12;
    const int q0 = qt * 64;
    const int qrow = q0 + wid * 16 + m16;   // this lane's q row (column of S^T)

    const unsigned short* Qb = Q  + (size_t)bh * 65536;
    const unsigned short* Kb = K  + (size_t)bh * 65536;
    const unsigned short* Vb = Vt + (size_t)bh * 65536;

    // kv-invariant staging source offsets (hole-free, all lanes active)
    int k_src[4], v_src[4];
    #pragma unroll
    for (int rd = 0; rd < 4; ++rd) {
        int id = rd * 256 + tid;
        int pos = id >> 3, dbs = id & 7;
        int db = dbs ^ (pos & 7);                 // un-swizzle: slot id holds this db
        k_src[rd] = pos * 64 + db * 8;
        int pb = id >> 6, d = id & 63;
        v_src[rd] = d * 1024 + pb * 8;
    }

    // Q fragments: B-operand of 16x16x32 (lane n=m16 holds dims quad*8..+8)
    short8 qf0 = *(const short8*)(Qb + (size_t)qrow * 64 + quad * 8);
    short8 qf1 = *(const short8*)(Qb + (size_t)qrow * 64 + 32 + quad * 8);

    f32x4 acc[4];
    #pragma unroll
    for (int nb = 0; nb < 4; nb++) acc[nb] = (f32x4){0.f, 0.f, 0.f, 0.f};
    float m_i = -3.0e38f, l_i = 0.f;

    for (int kv = 0; kv < 8; ++kv) {
        const int k0 = kv * 128;
        #pragma unroll
        for (int rd = 0; rd < 4; ++rd)
            GLDS(Kb + (size_t)k0 * 64 + k_src[rd], &Ks[(rd * 256 + tid) * 8]);
        #pragma unroll
        for (int rd = 0; rd < 4; ++rd)
            GLDS(Vb + (size_t)k0 + v_src[rd], &Vs[(rd * 256 + tid) * 8]);
        __syncthreads();

        // S^T = K·Q^T : sc[cb] rows = pos cb*16+quad*4+r, col = qrow(m16)
        f32x4 sc[8];
        #pragma unroll
        for (int cb = 0; cb < 8; ++cb) sc[cb] = (f32x4){0.f, 0.f, 0.f, 0.f};
        #pragma unroll
        for (int ks = 0; ks < 2; ++ks) {
            #pragma unroll
            for (int cb = 0; cb < 8; ++cb) {
                int pos = cb * 16 + m16;
                int slot = pos * 8 + ((ks * 4 + quad) ^ (m16 & 7));
                short8 a = *(const short8*)&Ks[slot * 8];
                sc[cb] = __builtin_amdgcn_mfma_f32_16x16x32_bf16(
                    a, (ks == 0) ? qf0 : qf1, sc[cb], 0, 0, 0);
            }
        }

        // scale + bias (float4 per cb) + running max (per-lane scalar)
        float mx = -3.0e38f;
        #pragma unroll
        for (int cb = 0; cb < 8; ++cb) {
            float4 bv = *(const float4*)(bias + (size_t)qrow * 1024 + k0 + cb * 16 + quad * 4);
            sc[cb][0] = sc[cb][0] * 0.125f + bv.x;
            sc[cb][1] = sc[cb][1] * 0.125f + bv.y;
            sc[cb][2] = sc[cb][2] * 0.125f + bv.z;
            sc[cb][3] = sc[cb][3] * 0.125f + bv.w;
            mx = fmaxf(mx, fmaxf(fmaxf(sc[cb][0], sc[cb][1]), fmaxf(sc[cb][2], sc[cb][3])));
        }
        mx = fmaxf(mx, __shfl_xor(mx, 16, 64));
        mx = fmaxf(mx, __shfl_xor(mx, 32, 64));
        float mnew = fmaxf(m_i, mx);
        float al = __expf(m_i - mnew);
        m_i = mnew;

        // exp + row-sum + pack P^T via v_perm_b32 truncation (2 elems/instr)
        float rs = 0.f;
        short4_ pf[8];
        #pragma unroll
        for (int cb = 0; cb < 8; ++cb) {
            float p0 = __expf(sc[cb][0] - m_i);
            float p1 = __expf(sc[cb][1] - m_i);
            float p2 = __expf(sc[cb][2] - m_i);
            float p3 = __expf(sc[cb][3] - m_i);
            rs += (p0 + p1) + (p2 + p3);
            uint2_ pd;
            pd[0] = __builtin_amdgcn_perm(__builtin_bit_cast(uint32_t, p1),
                                          __builtin_bit_cast(uint32_t, p0), 0x07060302u);
            pd[1] = __builtin_amdgcn_perm(__builtin_bit_cast(uint32_t, p3),
                                          __builtin_bit_cast(uint32_t, p2), 0x07060302u);
            pf[cb] = __builtin_bit_cast(short4_, pd);
        }
        rs += __shfl_xor(rs, 16, 64);
        rs += __shfl_xor(rs, 32, 64);
        l_i = l_i * al + rs;
        #pragma unroll
        for (int nb = 0; nb < 4; nb++) {
            acc[nb][0] *= al; acc[nb][1] *= al;
            acc[nb][2] *= al; acc[nb][3] *= al;
        }

        // O^T += V^T · P^T  (A = V^T frag from LDS, B = P^T in registers)
        #pragma unroll
        for (int ks = 0; ks < 8; ++ks) {
            #pragma unroll
            for (int nb = 0; nb < 4; ++nb) {
                int slot = (ks * 2 + (quad >> 1)) * 64 + nb * 16 + m16;
                short4_ av = *(const short4_*)&Vs[slot * 8 + (quad & 1) * 4];
                acc[nb] = __builtin_amdgcn_mfma_f32_16x16x16bf16_1k(av, pf[ks], acc[nb], 0, 0, 0);
            }
        }
        __syncthreads();
    }

    // epilogue: out = d[qrow]/l * O ; O^T C-layout: lane holds d = nb*16+quad*4+r
    float scl = dvec[qrow] / l_i;
    #pragma unroll
    for (int nb = 0; nb < 4; ++nb) {
        float4 o;
        o.x = acc[nb][0] * scl; o.y = acc[nb][1] * scl;
        o.z = acc[nb][2] * scl; o.w = acc[nb][3] * scl;
        *(float4*)(out + ((size_t)b * 1024 + qrow) * 768 + h * 64 + nb * 16 + quad * 4) = o;
    }
}

// ---------------- launch ----------------
// xb (bf16 x, 25165824 B) lives in the upper half of d_out; every gemm that
// reads an xb region precedes (stream order) any attn write to that region.
// Workspace is layout-adaptive on ws_size (constant across calls => the same
// work every call):
//   full path  (ws >= 79,036,416 B): wb + full-size q/k/vT  -> 1 gemm + 1 attn
//   chunk path (ws >= 22,413,312 B): wb + 4-batch q/k/vT    -> 4x(gemm+attn)
extern "C" void kernel_launch(void* const* d_in, const int* in_sizes, int n_in,
                              void* d_out, int out_size, void* d_ws, size_t ws_size,
                              hipStream_t stream) {
    const float* x     = (const float*)d_in[0];   // (16,1024,768)
    const float* w     = (const float*)d_in[1];   // (2304,768)
    const float* bqkv  = (const float*)d_in[2];   // (2304,)
    const float* dvec  = (const float*)d_in[3];   // (1024,)
    const float* bbias = (const float*)d_in[4];   // (1024,1024)
    float* out = (float*)d_out;

    char* ws = (char*)d_ws;
    unsigned short* wb = (unsigned short*)ws;                        // 2304*768 bf16
    unsigned short* xb = (unsigned short*)((char*)d_out + 25165824); // 16*1024*768 bf16

    cvt_kernel<<<6144, 256, 0, stream>>>(x, xb, 1572864);            // all x -> bf16
    cvt_kernel<<<864, 256, 0, stream>>>(w, wb, 221184);              // w -> bf16

    const size_t NEED_FULL = 3538944ull + 3ull * 25165824ull;        // 79,036,416
    if (ws_size >= NEED_FULL) {
        unsigned short* qb = (unsigned short*)(ws + 3538944);        // 16*12*1024*64
        unsigned short* kb = qb + 12582912;
        unsigned short* vb = kb + 12582912;                          // V^T (bh,64,1024)
        qkv_gemm<<<dim3(18, 128), 256, 0, stream>>>(xb, wb, bqkv, qb, kb, vb);
        attn_kernel<<<3072, 256, 0, stream>>>(qb, kb, vb, bbias, dvec, out, 24);
    } else {
        unsigned short* qb = (unsigned short*)(ws + 3538944);        // 4*12*1024*64
        unsigned short* kb = qb + 3145728;
        unsigned short* vb = kb + 3145728;                           // V^T (bh,64,1024)
        for (int c = 0; c < 4; ++c) {
            const unsigned short* xc = xb + (size_t)c * 3145728;     // 4 batches
            qkv_gemm<<<dim3(18, 32), 256, 0, stream>>>(xc, wb, bqkv, qb, kb, vb);
            attn_kernel<<<768, 256, 0, stream>>>(
                qb, kb, vb, bbias, dvec, out + (size_t)c * 3145728, 6);
        }
    }
}